// Round 12
// baseline (110.863 us; speedup 1.0000x reference)
//
#include <hip/hip_runtime.h>
#include <math.h>

#define SCALE 4.0f
#define H 128
#define E 64
#define TMAX 32

// d_ws layout (bytes):
//   [0      , 131072)  A-frag f16: f16x8 [mt8(8)][q(4)][kb(4)][lane(64)]
//   [131072 , 139264)  Uc: float4 {U0,U1,Cc,0} per gate row r (512 rows)
#define WS_UC_OFF  131072

typedef _Float16 f16x8 __attribute__((ext_vector_type(8)));   // 4 VGPRs
typedef __attribute__((ext_vector_type(4))) float f32x4;

__device__ __forceinline__ bool is_nanf(float x) {
    return (__float_as_uint(x) & 0x7fffffffu) > 0x7f800000u;
}
__device__ __forceinline__ float rcpf(float x) { return __builtin_amdgcn_rcpf(x); }
__device__ __forceinline__ float sigm(float x) { return rcpf(1.0f + __expf(-x)); }
__device__ __forceinline__ float tanhfast(float x) {
    return fmaf(2.0f, rcpf(1.0f + __expf(-2.0f * x)), -1.0f);
}

// ---------------- Pre-swizzle kernel (same layout as R8-R11) ----------------
__global__ __launch_bounds__(256)
void prep_kernel(const float* __restrict__ W_hh,
                 const float* __restrict__ W_ih,
                 const float* __restrict__ W_emb,
                 const float* __restrict__ b_emb,
                 const float* __restrict__ b_ih,
                 const float* __restrict__ b_hh,
                 char* __restrict__ ws)
{
    const int gid = blockIdx.x * 256 + threadIdx.x;
    if (gid < 8192) {
        const int lane = gid & 63;
        const int kb   = (gid >> 6) & 3;
        const int q    = (gid >> 8) & 3;
        const int w8   = gid >> 10;
        const int mt   = q * 8 + w8;
        const int row  = mt * 16 + (lane & 15);
        const int col0 = kb * 32 + (lane >> 4) * 8;
        const float* p = W_hh + (size_t)row * H + col0;
        f16x8 h8;
        #pragma unroll
        for (int j = 0; j < 8; ++j) h8[j] = (_Float16)p[j];
        *(f16x8*)(ws + (size_t)gid * 16) = h8;
    } else if (gid < 8192 + 512) {
        const int r = gid - 8192;
        const float* wr = W_ih + (size_t)r * E;
        float s0 = 0.f, s1 = 0.f, sc = 0.f;
        #pragma unroll 8
        for (int k = 0; k < E; ++k) {
            const float wv = wr[k];
            s0 += wv * W_emb[2 * k + 0];
            s1 += wv * W_emb[2 * k + 1];
            sc += wv * b_emb[k];
        }
        f32x4 v = {s0, s1, sc + b_ih[r] + b_hh[r], 0.0f};
        *(f32x4*)(ws + WS_UC_OFF + (size_t)r * 16) = v;
    }
}

// ---------------- Main kernel ----------------
// R12: ONE scene per block, 512 blocks, TWO blocks per CU
// (__launch_bounds__(512,4) caps VGPR at 128 -> 16 waves/CU). R11 showed
// the step is latency-chain-bound (halving LDS traffic changed nothing);
// this gives each CU two independent barrier/latency chains to overlap,
// at the proven 64-A-VGPR / 16-MFMA wave shape (R7's grid without R7's
// register pressure; per-CU MFMA issue ~300 cyc/step, pipe has room).
// B columns are 16 replicas of the single scene's h (f16).
__global__ __launch_bounds__(512, 4)
void lstm_disc_kernel(
    const float* __restrict__ observed,
    const float* __restrict__ prediction,
    const int* __restrict__ batch_split,
    const char* __restrict__ ws,
    const float* __restrict__ W1, const float* __restrict__ b1,
    const float* __restrict__ W2, const float* __restrict__ b2,
    const float* __restrict__ W3, const float* __restrict__ b3,
    float* __restrict__ out,
    int N, int T_obs, int T_total, int n_scenes)
{
    // h (single f16), parity double-buffered: [par][kb][32 f16].
    __shared__ __align__(16) _Float16 hT[2][4][32];
    __shared__ float h32[H];
    __shared__ float px[TMAX], py[TMAX];
    __shared__ float aA[TMAX], bA[TMAX];
    __shared__ int   mA[TMAX];
    __shared__ float x1s[H / 2];
    __shared__ float x2s[H / 4];

    const int tid  = threadIdx.x;
    const int wave = tid >> 6;
    const int lane = tid & 63;
    const int ln15 = lane & 15;
    const int g4   = lane >> 4;
    const int ea   = ln15 & 3;          // C reg index / unit sub-index
    const int rep  = ln15 >> 2;         // replica; rep 0 is the writer
    const int eu   = wave * 16 + g4 * 4 + ea;   // this lane's hidden unit
    const int scene = blockIdx.x;

    // ---- A fragments: 4 tiles (q) x 4 kb, coalesced dwordx4 ----
    f16x8 afr[4][4];
    #pragma unroll
    for (int q = 0; q < 4; ++q)
        #pragma unroll
        for (int kb = 0; kb < 4; ++kb) {
            const size_t slot = ((size_t)((wave * 4 + q) * 4 + kb) * 64 + lane) * 16;
            afr[q][kb] = *(const f16x8*)(ws + slot);
        }

    // ---- Folded input terms for unit eu ----
    float U0r[4], U1r[4], Ccr[4];
    #pragma unroll
    for (int q = 0; q < 4; ++q) {
        const f32x4 v = *(const f32x4*)(ws + WS_UC_OFF + (size_t)(eu + q * H) * 16);
        U0r[q] = v[0]; U1r[q] = v[1]; Ccr[q] = v[2];
    }

    // ---- Stage track, zero h buffers ----
    if (tid < TMAX && tid < T_total) {
        const int t = tid;
        const int agent = (scene < n_scenes) ? batch_split[scene] : 0;
        const float* src = (t < T_obs)
            ? (observed   + (size_t)t           * N * 2)
            : (prediction + (size_t)(t - T_obs) * N * 2);
        px[t] = src[(size_t)agent * 2 + 0];
        py[t] = src[(size_t)agent * 2 + 1];
    }
    if (tid < 128) ((int*)hT)[tid] = 0;   // 2*4*32 f16 = 128 dwords
    __syncthreads();

    if (tid < T_total - 1) {
        const int t = tid;
        const bool m = !(is_nanf(px[t]) || is_nanf(px[t + 1]));
        aA[t] = m ? SCALE * (px[t + 1] - px[t]) : 0.0f;
        bA[t] = m ? SCALE * (py[t + 1] - py[t]) : 0.0f;
        mA[t] = m ? 1 : 0;
    }

    // Writeback coords (rep 0 only): h[eu].
    const int wb_kb = eu >> 5;
    const int wb_k  = eu & 31;

    float c_st = 0.f, h_st = 0.f;
    __syncthreads();

    // ---- Recurrent loop: ONE barrier per step ----
    for (int t = 0; t < T_total - 1; ++t) {
        const int rp = t & 1, wp = rp ^ 1;

        const float aa = aA[t];
        const float bb = bA[t];
        const int   mm = mA[t];

        // B fragments: 4 distinct b128 addrs (g4), 16-lane broadcast.
        f16x8 bf[4];
        #pragma unroll
        for (int kb = 0; kb < 4; ++kb)
            bf[kb] = *(const f16x8*)&hT[rp][kb][g4 * 8];

        // 4 independent 4-deep chains.
        f32x4 acc[4];
        #pragma unroll
        for (int q = 0; q < 4; ++q) acc[q] = (f32x4){0.f, 0.f, 0.f, 0.f};
        #pragma unroll
        for (int kb = 0; kb < 4; ++kb)
            #pragma unroll
            for (int q = 0; q < 4; ++q)
                acc[q] = __builtin_amdgcn_mfma_f32_16x16x32_f16(afr[q][kb], bf[kb], acc[q], 0, 0, 0);

        // Epilogue: this lane's C element is reg 'ea' (row g4*4+ea).
        const float p0 = acc[0][ea] + Ccr[0] + aa * U0r[0] + bb * U1r[0];
        const float p1 = acc[1][ea] + Ccr[1] + aa * U0r[1] + bb * U1r[1];
        const float p2 = acc[2][ea] + Ccr[2] + aa * U0r[2] + bb * U1r[2];
        const float p3 = acc[3][ea] + Ccr[3] + aa * U0r[3] + bb * U1r[3];
        const float ig = sigm(p0);
        const float fg = sigm(p1);
        const float gg = tanhfast(p2);
        const float og = sigm(p3);
        const float c2 = fg * c_st + ig * gg;
        const float h2 = og * tanhfast(c2);
        if (mm) { c_st = c2; h_st = h2; }

        if (rep == 0) {   // one writer per unit
            hT[wp][wb_kb][wb_k] = (_Float16)h_st;
            if (t == T_total - 2) h32[eu] = h_st;
        }
        __syncthreads();
    }

    // ---- MLP head: 128 -> 64 -> 32 -> 1, relu ----
    if (tid < H / 2) {
        const float4* wr = (const float4*)(W1 + (size_t)tid * H);
        const float4* hv = (const float4*)h32;
        float sum = b1[tid];
        #pragma unroll
        for (int k = 0; k < H / 4; ++k) {
            const float4 w = wr[k], h = hv[k];
            sum += h.x * w.x + h.y * w.y + h.z * w.z + h.w * w.w;
        }
        x1s[tid] = fmaxf(sum, 0.f);
    }
    __syncthreads();
    if (tid < H / 4) {
        const float4* wr = (const float4*)(W2 + (size_t)tid * (H / 2));
        const float4* xv = (const float4*)x1s;
        float sum = b2[tid];
        #pragma unroll
        for (int k = 0; k < H / 8; ++k) {
            const float4 w = wr[k], x = xv[k];
            sum += x.x * w.x + x.y * w.y + x.z * w.z + x.w * w.w;
        }
        x2s[tid] = fmaxf(sum, 0.f);
    }
    __syncthreads();
    if (tid == 0 && scene < n_scenes) {
        float sum = b3[0];
        #pragma unroll
        for (int k = 0; k < H / 4; ++k) sum += x2s[k] * W3[k];
        out[scene] = fmaxf(sum, 0.f);
    }
}

extern "C" void kernel_launch(void* const* d_in, const int* in_sizes, int n_in,
                              void* d_out, int out_size, void* d_ws, size_t ws_size,
                              hipStream_t stream) {
    const float* observed   = (const float*)d_in[0];
    const float* prediction = (const float*)d_in[1];
    // d_in[2] = goals (unused by the reference computation)
    const int*   batch_split = (const int*)d_in[3];
    const float* W_emb = (const float*)d_in[4];
    const float* b_emb = (const float*)d_in[5];
    const float* W_ih  = (const float*)d_in[6];
    const float* W_hh  = (const float*)d_in[7];
    const float* b_ih  = (const float*)d_in[8];
    const float* b_hh  = (const float*)d_in[9];
    const float* W1 = (const float*)d_in[10];
    const float* b1 = (const float*)d_in[11];
    const float* W2 = (const float*)d_in[12];
    const float* b2 = (const float*)d_in[13];
    const float* W3 = (const float*)d_in[14];
    const float* b3 = (const float*)d_in[15];
    float* out = (float*)d_out;

    const int N       = in_sizes[2] / 2;               // goals is (N,2)
    const int T_obs   = in_sizes[0] / (2 * N);         // observed (T_obs,N,2)
    const int T_total = T_obs + in_sizes[1] / (2 * N); // 21
    const int n_scenes = in_sizes[3] - 1;              // batch_split has n+1 entries

    prep_kernel<<<34, 256, 0, stream>>>(
        W_hh, W_ih, W_emb, b_emb, b_ih, b_hh, (char*)d_ws);

    lstm_disc_kernel<<<n_scenes, 512, 0, stream>>>(   // 1 scene/block, 2 blocks/CU
        observed, prediction, batch_split, (const char*)d_ws,
        W1, b1, W2, b2, W3, b3,
        out, N, T_obs, T_total, n_scenes);
}

// Round 13
// 104.742 us; speedup vs baseline: 1.0584x; 1.0584x over previous
//
#include <hip/hip_runtime.h>
#include <math.h>

#define SCALE 4.0f
#define H 128
#define E 64
#define NS 2            // scenes per block
#define TMAX 32

// d_ws layout (bytes):
//   [0      , 131072)  A-frag f16: f16x8 [mt8(8)][q(4)][kb(4)][lane(64)]
//   [131072 , 139264)  Uc: float4 {U0,U1,Cc,0} per gate row r (512 rows)
#define WS_UC_OFF  131072

typedef _Float16 f16x8 __attribute__((ext_vector_type(8)));   // 4 VGPRs
typedef __attribute__((ext_vector_type(4))) float f32x4;

__device__ __forceinline__ bool is_nanf(float x) {
    return (__float_as_uint(x) & 0x7fffffffu) > 0x7f800000u;
}
__device__ __forceinline__ float rcpf(float x) { return __builtin_amdgcn_rcpf(x); }
__device__ __forceinline__ float sigm(float x) { return rcpf(1.0f + __expf(-x)); }
__device__ __forceinline__ float tanhfast(float x) {
    return fmaf(2.0f, rcpf(1.0f + __expf(-2.0f * x)), -1.0f);
}

// ---------------- Pre-swizzle kernel (same layout as R8-R12) ----------------
__global__ __launch_bounds__(256)
void prep_kernel(const float* __restrict__ W_hh,
                 const float* __restrict__ W_ih,
                 const float* __restrict__ W_emb,
                 const float* __restrict__ b_emb,
                 const float* __restrict__ b_ih,
                 const float* __restrict__ b_hh,
                 char* __restrict__ ws)
{
    const int gid = blockIdx.x * 256 + threadIdx.x;
    if (gid < 8192) {
        const int lane = gid & 63;
        const int kb   = (gid >> 6) & 3;
        const int q    = (gid >> 8) & 3;
        const int w8   = gid >> 10;
        const int mt   = q * 8 + w8;
        const int row  = mt * 16 + (lane & 15);
        const int col0 = kb * 32 + (lane >> 4) * 8;
        const float* p = W_hh + (size_t)row * H + col0;
        f16x8 h8;
        #pragma unroll
        for (int j = 0; j < 8; ++j) h8[j] = (_Float16)p[j];
        *(f16x8*)(ws + (size_t)gid * 16) = h8;
    } else if (gid < 8192 + 512) {
        const int r = gid - 8192;
        const float* wr = W_ih + (size_t)r * E;
        float s0 = 0.f, s1 = 0.f, sc = 0.f;
        #pragma unroll 8
        for (int k = 0; k < E; ++k) {
            const float wv = wr[k];
            s0 += wv * W_emb[2 * k + 0];
            s1 += wv * W_emb[2 * k + 1];
            sc += wv * b_emb[k];
        }
        f32x4 v = {s0, s1, sc + b_ih[r] + b_hh[r], 0.0f};
        *(f32x4*)(ws + WS_UC_OFF + (size_t)r * 16) = v;
    }
}

// ---------------- Main kernel ----------------
// R13 = R11 (single-f16 h, NS=2, 256 blocks, 16 MFMA/wave/step, one
// barrier/step) + step-0 specialization: h(0)=0, so step 0's pre-acts are
// just Ccr + a*U0 + b*U1 computed inline by every lane -- no ds_read, no
// MFMA, no hT zeroing, and one fewer pre-loop barrier. Loop runs t=1..19.
__global__ __launch_bounds__(512, 2)
void lstm_disc_kernel(
    const float* __restrict__ observed,
    const float* __restrict__ prediction,
    const int* __restrict__ batch_split,
    const char* __restrict__ ws,
    const float* __restrict__ W1, const float* __restrict__ b1,
    const float* __restrict__ W2, const float* __restrict__ b2,
    const float* __restrict__ W3, const float* __restrict__ b3,
    float* __restrict__ out,
    int N, int T_obs, int T_total, int n_scenes)
{
    // h (single f16), parity double-buffered: [par][kb][scene][32 f16].
    __shared__ __align__(16) _Float16 hT[2][4][NS][32];
    __shared__ float h32[NS][H];
    __shared__ float px[NS][TMAX], py[NS][TMAX];
    __shared__ float aA[NS][TMAX], bA[NS][TMAX];
    __shared__ int   mA[NS][TMAX];
    __shared__ float x1s[NS][H / 2];
    __shared__ float x2s[NS][H / 4];

    const int tid  = threadIdx.x;
    const int wave = tid >> 6;
    const int lane = tid & 63;
    const int ln15 = lane & 15;
    const int g4   = lane >> 4;
    const int esc  = ln15 & 1;          // this lane's scene
    const int ea   = (ln15 >> 1) & 3;   // C reg index / unit sub-index
    const int rep  = ln15 >> 3;         // replica; rep 0 is the writer
    const int eu   = wave * 16 + g4 * 4 + ea;   // this lane's hidden unit
    const int sc0  = blockIdx.x * NS;

    // ---- A fragments: 4 tiles (q) x 4 kb, coalesced dwordx4 ----
    f16x8 afr[4][4];
    #pragma unroll
    for (int q = 0; q < 4; ++q)
        #pragma unroll
        for (int kb = 0; kb < 4; ++kb) {
            const size_t slot = ((size_t)((wave * 4 + q) * 4 + kb) * 64 + lane) * 16;
            afr[q][kb] = *(const f16x8*)(ws + slot);
        }

    // ---- Folded input terms for unit eu ----
    float U0r[4], U1r[4], Ccr[4];
    #pragma unroll
    for (int q = 0; q < 4; ++q) {
        const f32x4 v = *(const f32x4*)(ws + WS_UC_OFF + (size_t)(eu + q * H) * 16);
        U0r[q] = v[0]; U1r[q] = v[1]; Ccr[q] = v[2];
    }

    // ---- Stage tracks ----
    if (tid < NS * TMAX) {
        const int s = tid >> 5, t = tid & 31;
        const int scene = sc0 + s;
        const int agent = (scene < n_scenes) ? batch_split[scene] : 0;
        if (t < T_total) {
            const float* src = (t < T_obs)
                ? (observed   + (size_t)t           * N * 2)
                : (prediction + (size_t)(t - T_obs) * N * 2);
            px[s][t] = src[(size_t)agent * 2 + 0];
            py[s][t] = src[(size_t)agent * 2 + 1];
        }
    }
    __syncthreads();

    // Velocity/mask arrays for t >= 1 (consumed after the next barrier).
    if (tid < NS * TMAX) {
        const int s = tid >> 5, t = tid & 31;
        if (t < T_total - 1) {
            const bool m = !(is_nanf(px[s][t]) || is_nanf(px[s][t + 1]));
            aA[s][t] = m ? SCALE * (px[s][t + 1] - px[s][t]) : 0.0f;
            bA[s][t] = m ? SCALE * (py[s][t + 1] - py[s][t]) : 0.0f;
            mA[s][t] = m ? 1 : 0;
        }
    }

    // Writeback coords (rep 0 only): h[eu] of scene esc.
    const int wb_kb = eu >> 5;
    const int wb_k  = eu & 31;

    // ---- Step 0 inline (h=0: no MFMA, no exchange needed) ----
    float c_st = 0.f, h_st = 0.f;
    {
        const float p0x = px[esc][0], p1x = px[esc][1];
        const bool  m0  = !(is_nanf(p0x) || is_nanf(p1x));
        const float aa  = m0 ? SCALE * (p1x - p0x) : 0.0f;
        const float bb  = m0 ? SCALE * (py[esc][1] - py[esc][0]) : 0.0f;
        const float p0 = Ccr[0] + aa * U0r[0] + bb * U1r[0];
        const float p1 = Ccr[1] + aa * U0r[1] + bb * U1r[1];
        const float p2 = Ccr[2] + aa * U0r[2] + bb * U1r[2];
        const float p3 = Ccr[3] + aa * U0r[3] + bb * U1r[3];
        const float ig = sigm(p0);
        const float fg = sigm(p1);
        const float gg = tanhfast(p2);
        const float og = sigm(p3);
        const float c2 = fg * 0.f + ig * gg;
        const float h2 = og * tanhfast(c2);
        if (m0) { c_st = c2; h_st = h2; }
        if (rep == 0)                   // populate parity 1 for the t=1 read
            hT[1][wb_kb][esc][wb_k] = (_Float16)h_st;
    }
    __syncthreads();

    // ---- Recurrent loop: t = 1 .. T_total-2, ONE barrier per step ----
    for (int t = 1; t < T_total - 1; ++t) {
        const int rp = t & 1, wp = rp ^ 1;

        const float aa = aA[esc][t];
        const float bb = bA[esc][t];
        const int   mm = mA[esc][t];

        // B fragments: 8 distinct b128 addrs, 8-lane broadcast, conflict-free.
        f16x8 bf[4];
        #pragma unroll
        for (int kb = 0; kb < 4; ++kb)
            bf[kb] = *(const f16x8*)&hT[rp][kb][esc][g4 * 8];

        // 4 independent 4-deep chains.
        f32x4 acc[4];
        #pragma unroll
        for (int q = 0; q < 4; ++q) acc[q] = (f32x4){0.f, 0.f, 0.f, 0.f};
        #pragma unroll
        for (int kb = 0; kb < 4; ++kb)
            #pragma unroll
            for (int q = 0; q < 4; ++q)
                acc[q] = __builtin_amdgcn_mfma_f32_16x16x32_f16(afr[q][kb], bf[kb], acc[q], 0, 0, 0);

        // Epilogue: this lane's C element is reg 'ea' (row g4*4+ea), col ln15.
        const float p0 = acc[0][ea] + Ccr[0] + aa * U0r[0] + bb * U1r[0];
        const float p1 = acc[1][ea] + Ccr[1] + aa * U0r[1] + bb * U1r[1];
        const float p2 = acc[2][ea] + Ccr[2] + aa * U0r[2] + bb * U1r[2];
        const float p3 = acc[3][ea] + Ccr[3] + aa * U0r[3] + bb * U1r[3];
        const float ig = sigm(p0);
        const float fg = sigm(p1);
        const float gg = tanhfast(p2);
        const float og = sigm(p3);
        const float c2 = fg * c_st + ig * gg;
        const float h2 = og * tanhfast(c2);
        if (mm) { c_st = c2; h_st = h2; }

        if (rep == 0) {   // one writer per unit; 2-way same-dword u16: free
            hT[wp][wb_kb][esc][wb_k] = (_Float16)h_st;
            if (t == T_total - 2) h32[esc][eu] = h_st;
        }
        __syncthreads();
    }

    // ---- MLP head: 128 -> 64 -> 32 -> 1, relu (NS=2 scenes) ----
    if (tid < NS * (H / 2)) {
        const int s = tid >> 6, u = tid & 63;
        const float4* wr = (const float4*)(W1 + (size_t)u * H);
        const float4* hv = (const float4*)h32[s];
        float sum = b1[u];
        #pragma unroll
        for (int k = 0; k < H / 4; ++k) {
            const float4 w = wr[k], h = hv[k];
            sum += h.x * w.x + h.y * w.y + h.z * w.z + h.w * w.w;
        }
        x1s[s][u] = fmaxf(sum, 0.f);
    }
    __syncthreads();
    if (tid < NS * (H / 4)) {
        const int s = tid >> 5, u = tid & 31;
        const float4* wr = (const float4*)(W2 + (size_t)u * (H / 2));
        const float4* xv = (const float4*)x1s[s];
        float sum = b2[u];
        #pragma unroll
        for (int k = 0; k < H / 8; ++k) {
            const float4 w = wr[k], x = xv[k];
            sum += x.x * w.x + x.y * w.y + x.z * w.z + x.w * w.w;
        }
        x2s[s][u] = fmaxf(sum, 0.f);
    }
    __syncthreads();
    if (tid < NS) {
        const int scene = sc0 + tid;
        if (scene < n_scenes) {
            float sum = b3[0];
            #pragma unroll
            for (int k = 0; k < H / 4; ++k) sum += x2s[tid][k] * W3[k];
            out[scene] = fmaxf(sum, 0.f);
        }
    }
}

extern "C" void kernel_launch(void* const* d_in, const int* in_sizes, int n_in,
                              void* d_out, int out_size, void* d_ws, size_t ws_size,
                              hipStream_t stream) {
    const float* observed   = (const float*)d_in[0];
    const float* prediction = (const float*)d_in[1];
    // d_in[2] = goals (unused by the reference computation)
    const int*   batch_split = (const int*)d_in[3];
    const float* W_emb = (const float*)d_in[4];
    const float* b_emb = (const float*)d_in[5];
    const float* W_ih  = (const float*)d_in[6];
    const float* W_hh  = (const float*)d_in[7];
    const float* b_ih  = (const float*)d_in[8];
    const float* b_hh  = (const float*)d_in[9];
    const float* W1 = (const float*)d_in[10];
    const float* b1 = (const float*)d_in[11];
    const float* W2 = (const float*)d_in[12];
    const float* b2 = (const float*)d_in[13];
    const float* W3 = (const float*)d_in[14];
    const float* b3 = (const float*)d_in[15];
    float* out = (float*)d_out;

    const int N       = in_sizes[2] / 2;               // goals is (N,2)
    const int T_obs   = in_sizes[0] / (2 * N);         // observed (T_obs,N,2)
    const int T_total = T_obs + in_sizes[1] / (2 * N); // 21
    const int n_scenes = in_sizes[3] - 1;              // batch_split has n+1 entries

    prep_kernel<<<34, 256, 0, stream>>>(
        W_hh, W_ih, W_emb, b_emb, b_ih, b_hh, (char*)d_ws);

    const int nblocks = (n_scenes + NS - 1) / NS;      // 256 blocks, 1/CU
    lstm_disc_kernel<<<nblocks, 512, 0, stream>>>(
        observed, prediction, batch_split, (const char*)d_ws,
        W1, b1, W2, b2, W3, b3,
        out, N, T_obs, T_total, n_scenes);
}